// Round 1
// baseline (572.411 us; speedup 1.0000x reference)
//
#include <hip/hip_runtime.h>
#include <math.h>

#define RPB 4          // rows per block (one wave per block)
#define OBS 114

__device__ __forceinline__ float fast_tanh(float x) {
    float e = __expf(2.0f * x);
    return 1.0f - 2.0f * __builtin_amdgcn_rcpf(e + 1.0f);
}

__device__ __forceinline__ void red2(float& a, float& b) {
#pragma unroll
    for (int m = 32; m >= 1; m >>= 1) {
        a += __shfl_xor(a, m, 64);
        b += __shfl_xor(b, m, 64);
    }
}

__device__ __forceinline__ void red3(float& a, float& b, float& c) {
#pragma unroll
    for (int m = 32; m >= 1; m >>= 1) {
        a += __shfl_xor(a, m, 64);
        b += __shfl_xor(b, m, 64);
        c += __shfl_xor(c, m, 64);
    }
}

__device__ __forceinline__ float f4c(const float4& v, int j) {
    return j == 0 ? v.x : j == 1 ? v.y : j == 2 ? v.z : v.w;
}

// One attention stream with online softmax over agents.
// logit = (sum(q*g*t) - mean*sum(q*g))/sigma + sum(q*be)
template<int K, int NA>
__device__ __forceinline__ void attn_stream(
    const float* __restrict__ W, const float* __restrict__ bb,
    const float* __restrict__ gp, const float* __restrict__ be,
    const float (*s_xin)[OBS], int xoff,
    const float (&q0)[RPB], const float (&q1)[RPB],
    float (*s_x4)[400], int oseg,
    int h0, int h1, float act1f, bool act1, int lane)
{
    float w0[K], w1[K];
#pragma unroll
    for (int k = 0; k < K; ++k) { w0[k] = W[k*100 + h0]; w1[k] = W[k*100 + h1]; }
    float b0 = bb[h0], b1 = bb[h1];
    float g0 = gp[h0], g1 = gp[h1];
    float be0 = be[h0], be1 = be[h1];

    float C1[RPB], C2[RPB], qg0[RPB], qg1[RPB];
#pragma unroll
    for (int r = 0; r < RPB; ++r) {
        qg0[r] = q0[r] * g0;
        qg1[r] = q1[r] * g1;
        float c1 = qg0[r] + act1f * qg1[r];
        float c2 = q0[r] * be0 + act1f * (q1[r] * be1);
        red2(c1, c2);
        C1[r] = c1; C2[r] = c2;
    }
    float m[RPB], s[RPB], v0[RPB], v1[RPB];
#pragma unroll
    for (int r = 0; r < RPB; ++r) { m[r] = -INFINITY; s[r] = 0.f; v0[r] = 0.f; v1[r] = 0.f; }

    for (int n = 0; n < NA; ++n) {
#pragma unroll
        for (int r = 0; r < RPB; ++r) {
            float t0 = b0, t1 = b1;
#pragma unroll
            for (int k = 0; k < K; ++k) {
                float xk = s_xin[r][xoff + n*K + k];
                t0 = fmaf(xk, w0[k], t0);
                t1 = fmaf(xk, w1[k], t1);
            }
            t0 = fast_tanh(t0);
            t1 = fast_tanh(t1);
            float sa = t0 + act1f * t1;
            float sq = t0*t0 + act1f * (t1*t1);
            float sd = qg0[r]*t0 + act1f * (qg1[r]*t1);
            red3(sa, sq, sd);
            float mean = sa * 0.01f;
            float var  = sq * 0.01f - mean*mean;
            float rinv = __builtin_amdgcn_rsqf(var + 1e-5f);
            float logit = (sd - mean * C1[r]) * rinv + C2[r];
            float mn = fmaxf(m[r], logit);
            float cc = __expf(m[r] - mn);
            float w  = __expf(logit - mn);
            m[r] = mn;
            s[r] = s[r]*cc + w;
            float e0 = (t0 - mean) * rinv * g0 + be0;
            float e1 = (t1 - mean) * rinv * g1 + be1;
            v0[r] = v0[r]*cc + w*e0;
            v1[r] = v1[r]*cc + w*e1;
        }
    }
#pragma unroll
    for (int r = 0; r < RPB; ++r) {
        float inv = __builtin_amdgcn_rcpf(s[r]);
        s_x4[r][oseg + h0] = v0[r] * inv;
        if (act1) s_x4[r][oseg + lane + 64] = v1[r] * inv;
    }
}

__global__ __launch_bounds__(64)
void obs_encoder_kernel(const float* __restrict__ in,
    const float* __restrict__ sW, const float* __restrict__ sb, const float* __restrict__ sg, const float* __restrict__ sbe,
    const float* __restrict__ oW, const float* __restrict__ ob, const float* __restrict__ og, const float* __restrict__ obe,
    const float* __restrict__ lW, const float* __restrict__ lb, const float* __restrict__ lg, const float* __restrict__ lbe,
    const float* __restrict__ gW, const float* __restrict__ gb, const float* __restrict__ gg_, const float* __restrict__ gbe,
    const float* __restrict__ Ac, const float* __restrict__ Lc,
    const float* __restrict__ fcW, const float* __restrict__ fcb, const float* __restrict__ fcg, const float* __restrict__ fcbe,
    const float* __restrict__ f1W, const float* __restrict__ f1b, const float* __restrict__ f1g, const float* __restrict__ f1be,
    const float* __restrict__ f2W, const float* __restrict__ f2b, const float* __restrict__ f2g, const float* __restrict__ f2be,
    float* __restrict__ out, int B)
{
    const int lane = threadIdx.x;
    const int h0 = lane;
    const bool act1 = lane < 36;
    const float act1f = act1 ? 1.f : 0.f;
    const int h1 = act1 ? lane + 64 : 0;   // clamped index for safe loads
    const int row0 = blockIdx.x * RPB;

    __shared__ __align__(16) float s_xin[RPB][OBS];
    __shared__ __align__(16) float s_emb[RPB][100];
    __shared__ __align__(16) float s_x4[RPB][400];
    __shared__ __align__(16) float s_h1[RPB][100];

    // ---- load input rows into LDS ----
#pragma unroll
    for (int r = 0; r < RPB; ++r) {
        int row = row0 + r;
        const float* src = in + (size_t)row * OBS;
        if (row < B) {
            for (int i = lane; i < OBS; i += 64) s_xin[r][i] = src[i];
        } else {
            for (int i = lane; i < OBS; i += 64) s_xin[r][i] = 0.f;
        }
    }
    __syncthreads();

    // ---- self encoder -> s_emb ----
    {
        float w0[4], w1[4];
#pragma unroll
        for (int k = 0; k < 4; ++k) { w0[k] = sW[k*100+h0]; w1[k] = sW[k*100+h1]; }
        float b0 = sb[h0], b1 = sb[h1];
        float g0 = sg[h0], g1 = sg[h1];
        float be0 = sbe[h0], be1 = sbe[h1];
#pragma unroll
        for (int r = 0; r < RPB; ++r) {
            float t0 = b0, t1 = b1;
#pragma unroll
            for (int k = 0; k < 4; ++k) {
                float xk = s_xin[r][k];
                t0 = fmaf(xk, w0[k], t0);
                t1 = fmaf(xk, w1[k], t1);
            }
            t0 = fast_tanh(t0); t1 = fast_tanh(t1);
            float sa = t0 + act1f*t1;
            float sq = t0*t0 + act1f*(t1*t1);
            red2(sa, sq);
            float mean = sa*0.01f;
            float var  = sq*0.01f - mean*mean;
            float rinv = __builtin_amdgcn_rsqf(var + 1e-5f);
            s_emb[r][h0] = (t0-mean)*rinv*g0 + be0;
            if (act1) s_emb[r][lane+64] = (t1-mean)*rinv*g1 + be1;
        }
    }
    __syncthreads();

    // ---- qa = s_emb@Ac, ql = s_emb@Lc, tg = s_emb@fcW (fused k-loop) ----
    float qa0[RPB], qa1[RPB], ql0[RPB], ql1[RPB], tg0[RPB], tg1[RPB];
#pragma unroll
    for (int r = 0; r < RPB; ++r) { qa0[r]=qa1[r]=ql0[r]=ql1[r]=tg0[r]=tg1[r]=0.f; }
#pragma unroll 1
    for (int k4 = 0; k4 < 25; ++k4) {
        float4 sv[RPB];
#pragma unroll
        for (int r = 0; r < RPB; ++r) sv[r] = *(const float4*)&s_emb[r][k4*4];
#pragma unroll
        for (int j = 0; j < 4; ++j) {
            int k = k4*4 + j;
            float a0 = Ac[k*100+h0],  a1 = Ac[k*100+h1];
            float l0 = Lc[k*100+h0],  l1 = Lc[k*100+h1];
            float f0 = fcW[k*100+h0], f1 = fcW[k*100+h1];
#pragma unroll
            for (int r = 0; r < RPB; ++r) {
                float sk = f4c(sv[r], j);
                qa0[r] = fmaf(sk, a0, qa0[r]);
                qa1[r] = fmaf(sk, a1, qa1[r]);
                ql0[r] = fmaf(sk, l0, ql0[r]);
                ql1[r] = fmaf(sk, l1, ql1[r]);
                tg0[r] = fmaf(sk, f0, tg0[r]);
                tg1[r] = fmaf(sk, f1, tg1[r]);
            }
        }
    }

    // ---- gi = LN(tanh(tg + fcb)) -> s_x4[:, 0:100] ----
    {
        float b0 = fcb[h0], b1 = fcb[h1];
        float g0 = fcg[h0], g1 = fcg[h1];
        float be0 = fcbe[h0], be1 = fcbe[h1];
#pragma unroll
        for (int r = 0; r < RPB; ++r) {
            float t0 = fast_tanh(tg0[r] + b0);
            float t1 = fast_tanh(tg1[r] + b1);
            float sa = t0 + act1f*t1;
            float sq = t0*t0 + act1f*(t1*t1);
            red2(sa, sq);
            float mean = sa*0.01f;
            float var  = sq*0.01f - mean*mean;
            float rinv = __builtin_amdgcn_rsqf(var + 1e-5f);
            s_x4[r][h0] = (t0-mean)*rinv*g0 + be0;
            if (act1) s_x4[r][lane+64] = (t1-mean)*rinv*g1 + be1;
        }
    }

    // ---- attention streams (online softmax; note ql reused for goal per ref bug) ----
    attn_stream<2,15>(oW, ob, og,  obe, s_xin, 52, qa0, qa1, s_x4, 100, h0, h1, act1f, act1, lane);
    attn_stream<3,16>(lW, lb, lg,  lbe, s_xin, 4,  ql0, ql1, s_x4, 200, h0, h1, act1f, act1, lane);
    attn_stream<2,16>(gW, gb, gg_, gbe, s_xin, 82, ql0, ql1, s_x4, 300, h0, h1, act1f, act1, lane);
    __syncthreads();

    // ---- f1: [400] -> [100] ----
    float t10[RPB], t11[RPB];
#pragma unroll
    for (int r = 0; r < RPB; ++r) { t10[r]=0.f; t11[r]=0.f; }
#pragma unroll 1
    for (int k4 = 0; k4 < 100; ++k4) {
        float4 xv[RPB];
#pragma unroll
        for (int r = 0; r < RPB; ++r) xv[r] = *(const float4*)&s_x4[r][k4*4];
#pragma unroll
        for (int j = 0; j < 4; ++j) {
            int k = k4*4 + j;
            float w0 = f1W[k*100+h0], w1 = f1W[k*100+h1];
#pragma unroll
            for (int r = 0; r < RPB; ++r) {
                float xk = f4c(xv[r], j);
                t10[r] = fmaf(xk, w0, t10[r]);
                t11[r] = fmaf(xk, w1, t11[r]);
            }
        }
    }
    {
        float b0 = f1b[h0], b1 = f1b[h1];
        float g0 = f1g[h0], g1 = f1g[h1];
        float be0 = f1be[h0], be1 = f1be[h1];
#pragma unroll
        for (int r = 0; r < RPB; ++r) {
            float t0 = fast_tanh(t10[r] + b0);
            float t1 = fast_tanh(t11[r] + b1);
            float sa = t0 + act1f*t1;
            float sq = t0*t0 + act1f*(t1*t1);
            red2(sa, sq);
            float mean = sa*0.01f;
            float var  = sq*0.01f - mean*mean;
            float rinv = __builtin_amdgcn_rsqf(var + 1e-5f);
            s_h1[r][h0] = (t0-mean)*rinv*g0 + be0;
            if (act1) s_h1[r][lane+64] = (t1-mean)*rinv*g1 + be1;
        }
    }
    __syncthreads();

    // ---- f2: [100] -> [100] -> out ----
    float t20[RPB], t21[RPB];
#pragma unroll
    for (int r = 0; r < RPB; ++r) { t20[r]=0.f; t21[r]=0.f; }
#pragma unroll 1
    for (int k4 = 0; k4 < 25; ++k4) {
        float4 hv[RPB];
#pragma unroll
        for (int r = 0; r < RPB; ++r) hv[r] = *(const float4*)&s_h1[r][k4*4];
#pragma unroll
        for (int j = 0; j < 4; ++j) {
            int k = k4*4 + j;
            float w0 = f2W[k*100+h0], w1 = f2W[k*100+h1];
#pragma unroll
            for (int r = 0; r < RPB; ++r) {
                float xk = f4c(hv[r], j);
                t20[r] = fmaf(xk, w0, t20[r]);
                t21[r] = fmaf(xk, w1, t21[r]);
            }
        }
    }
    {
        float b0 = f2b[h0], b1 = f2b[h1];
        float g0 = f2g[h0], g1 = f2g[h1];
        float be0 = f2be[h0], be1 = f2be[h1];
#pragma unroll
        for (int r = 0; r < RPB; ++r) {
            int row = row0 + r;
            float t0 = fast_tanh(t20[r] + b0);
            float t1 = fast_tanh(t21[r] + b1);
            float sa = t0 + act1f*t1;
            float sq = t0*t0 + act1f*(t1*t1);
            red2(sa, sq);
            float mean = sa*0.01f;
            float var  = sq*0.01f - mean*mean;
            float rinv = __builtin_amdgcn_rsqf(var + 1e-5f);
            if (row < B) {
                out[(size_t)row*100 + h0] = (t0-mean)*rinv*g0 + be0;
                if (act1) out[(size_t)row*100 + lane + 64] = (t1-mean)*rinv*g1 + be1;
            }
        }
    }
}

extern "C" void kernel_launch(void* const* d_in, const int* in_sizes, int n_in,
                              void* d_out, int out_size, void* d_ws, size_t ws_size,
                              hipStream_t stream) {
    const float* in  = (const float*)d_in[0];
    // d_in[1] is agent_num (N=16 hardcoded via template params / offsets)
    const float* sW  = (const float*)d_in[2];
    const float* sb  = (const float*)d_in[3];
    const float* sg  = (const float*)d_in[4];
    const float* sbe = (const float*)d_in[5];
    const float* oW  = (const float*)d_in[6];
    const float* ob  = (const float*)d_in[7];
    const float* og  = (const float*)d_in[8];
    const float* obe = (const float*)d_in[9];
    const float* lW  = (const float*)d_in[10];
    const float* lb  = (const float*)d_in[11];
    const float* lg  = (const float*)d_in[12];
    const float* lbe = (const float*)d_in[13];
    const float* gW  = (const float*)d_in[14];
    const float* gb  = (const float*)d_in[15];
    const float* gg  = (const float*)d_in[16];
    const float* gbe = (const float*)d_in[17];
    const float* Ac  = (const float*)d_in[18];
    const float* Lc  = (const float*)d_in[19];
    const float* fcW = (const float*)d_in[20];
    const float* fcb = (const float*)d_in[21];
    const float* fcg = (const float*)d_in[22];
    const float* fcbe= (const float*)d_in[23];
    const float* f1W = (const float*)d_in[24];
    const float* f1b = (const float*)d_in[25];
    const float* f1g = (const float*)d_in[26];
    const float* f1be= (const float*)d_in[27];
    const float* f2W = (const float*)d_in[28];
    const float* f2b = (const float*)d_in[29];
    const float* f2g = (const float*)d_in[30];
    const float* f2be= (const float*)d_in[31];
    float* out = (float*)d_out;

    int B = in_sizes[0] / OBS;
    int blocks = (B + RPB - 1) / RPB;
    obs_encoder_kernel<<<blocks, 64, 0, stream>>>(in,
        sW, sb, sg, sbe, oW, ob, og, obe, lW, lb, lg, lbe, gW, gb, gg, gbe,
        Ac, Lc, fcW, fcb, fcg, fcbe, f1W, f1b, f1g, f1be, f2W, f2b, f2g, f2be,
        out, B);
}

// Round 2
// 556.926 us; speedup vs baseline: 1.0278x; 1.0278x over previous
//
#include <hip/hip_runtime.h>
#include <math.h>

#define RPB 8          // rows per block (one wave per block)
#define OBS 114

__device__ __forceinline__ float fast_tanh(float x) {
    float e = __expf(2.0f * x);
    return 1.0f - 2.0f * __builtin_amdgcn_rcpf(e + 1.0f);
}

// DPP-based partial reduction: 4 VALU-pipe steps cover each 16-lane row,
// then 2 DS shuffles cross the rows/halves. vs 6 DS shuffles before.
template<int CTRL>
__device__ __forceinline__ float dpp_add(float x) {
    int y = __builtin_amdgcn_update_dpp(0, __float_as_int(x), CTRL, 0xF, 0xF, true);
    return x + __int_as_float(y);
}

__device__ __forceinline__ float wave_sum(float x) {
    x = dpp_add<0xB1>(x);    // quad_perm [1,0,3,2]  (xor 1)
    x = dpp_add<0x4E>(x);    // quad_perm [2,3,0,1]  (xor 2)
    x = dpp_add<0x124>(x);   // row_ror:4
    x = dpp_add<0x128>(x);   // row_ror:8  -> every lane has its row-of-16 sum
    x += __shfl_xor(x, 16, 64);
    x += __shfl_xor(x, 32, 64);
    return x;
}

__device__ __forceinline__ float f4c(const float4& v, int j) {
    return j == 0 ? v.x : j == 1 ? v.y : j == 2 ? v.z : v.w;
}

// One attention stream with online softmax over agents.
// logit = (sum(q*g*t) - mean*sum(q*g))/sigma + sum(q*be)
// Agent inputs read straight from global with wave-uniform addresses (s_load).
template<int K, int NA>
__device__ __forceinline__ void attn_stream(
    const float* __restrict__ W, const float* __restrict__ bb,
    const float* __restrict__ gp, const float* __restrict__ be,
    const float* __restrict__ in, int row0, int B, int xoff,
    const float (&q0)[RPB], const float (&q1)[RPB],
    float (*s_x4)[400], int oseg,
    int h0, int h1, float act1f, bool act1, int lane)
{
    float w0[K], w1[K];
#pragma unroll
    for (int k = 0; k < K; ++k) { w0[k] = W[k*100 + h0]; w1[k] = W[k*100 + h1]; }
    float b0 = bb[h0], b1 = bb[h1];
    float g0 = gp[h0], g1 = gp[h1];
    float be0 = be[h0], be1 = be[h1];

    float C1[RPB], C2[RPB], qg0[RPB], qg1[RPB];
#pragma unroll
    for (int r = 0; r < RPB; ++r) {
        qg0[r] = q0[r] * g0;
        qg1[r] = act1f * (q1[r] * g1);   // zeroed on inactive lanes
        C1[r] = wave_sum(qg0[r] + qg1[r]);
        C2[r] = wave_sum(q0[r] * be0 + act1f * (q1[r] * be1));
    }
    float m[RPB], s[RPB], v0[RPB], v1[RPB];
#pragma unroll
    for (int r = 0; r < RPB; ++r) { m[r] = -INFINITY; s[r] = 0.f; v0[r] = 0.f; v1[r] = 0.f; }

#pragma unroll 1
    for (int n = 0; n < NA; ++n) {
#pragma unroll
        for (int r = 0; r < RPB; ++r) {
            int row = min(row0 + r, B - 1);
            size_t base = (size_t)row * OBS + xoff + n * K;
            float t0 = b0, t1 = b1;
#pragma unroll
            for (int k = 0; k < K; ++k) {
                float xk = in[base + k];          // wave-uniform -> s_load
                t0 = fmaf(xk, w0[k], t0);
                t1 = fmaf(xk, w1[k], t1);
            }
            t0 = fast_tanh(t0);
            t1 = fast_tanh(t1);
            float sa = wave_sum(t0 + act1f * t1);
            float sq = wave_sum(t0*t0 + act1f * (t1*t1));
            float sd = wave_sum(qg0[r]*t0 + qg1[r]*t1);
            float mean = sa * 0.01f;
            float var  = sq * 0.01f - mean*mean;
            float rinv = __builtin_amdgcn_rsqf(var + 1e-5f);
            float logit = (sd - mean * C1[r]) * rinv + C2[r];
            float mn = fmaxf(m[r], logit);
            float cc = __expf(m[r] - mn);
            float w  = __expf(logit - mn);
            m[r] = mn;
            s[r] = s[r]*cc + w;
            float e0 = (t0 - mean) * rinv * g0 + be0;
            float e1 = (t1 - mean) * rinv * g1 + be1;
            v0[r] = v0[r]*cc + w*e0;
            v1[r] = v1[r]*cc + w*e1;
        }
    }
#pragma unroll
    for (int r = 0; r < RPB; ++r) {
        float inv = __builtin_amdgcn_rcpf(s[r]);
        s_x4[r][oseg + h0] = v0[r] * inv;
        if (act1) s_x4[r][oseg + lane + 64] = v1[r] * inv;
    }
}

__global__ __launch_bounds__(64)
void obs_encoder_kernel(const float* __restrict__ in,
    const float* __restrict__ sW, const float* __restrict__ sb, const float* __restrict__ sg, const float* __restrict__ sbe,
    const float* __restrict__ oW, const float* __restrict__ ob, const float* __restrict__ og, const float* __restrict__ obe,
    const float* __restrict__ lW, const float* __restrict__ lb, const float* __restrict__ lg, const float* __restrict__ lbe,
    const float* __restrict__ gW, const float* __restrict__ gb, const float* __restrict__ gg_, const float* __restrict__ gbe,
    const float* __restrict__ Ac, const float* __restrict__ Lc,
    const float* __restrict__ fcW, const float* __restrict__ fcb, const float* __restrict__ fcg, const float* __restrict__ fcbe,
    const float* __restrict__ f1W, const float* __restrict__ f1b, const float* __restrict__ f1g, const float* __restrict__ f1be,
    const float* __restrict__ f2W, const float* __restrict__ f2b, const float* __restrict__ f2g, const float* __restrict__ f2be,
    float* __restrict__ out, int B)
{
    const int lane = threadIdx.x;
    const int h0 = lane;
    const bool act1 = lane < 36;
    const float act1f = act1 ? 1.f : 0.f;
    const int h1 = act1 ? lane + 64 : 0;   // clamped index for safe loads
    const int row0 = blockIdx.x * RPB;

    // Single-wave block: no __syncthreads needed; DS ordering via waitcnt.
    __shared__ __align__(16) float s_x4[RPB][400];
    __shared__ __align__(16) float s_emb[RPB][100];   // reused for h1 after f1

    // ---- self encoder -> s_emb (inputs via wave-uniform scalar loads) ----
    {
        float w0[4], w1[4];
#pragma unroll
        for (int k = 0; k < 4; ++k) { w0[k] = sW[k*100+h0]; w1[k] = sW[k*100+h1]; }
        float b0 = sb[h0], b1 = sb[h1];
        float g0 = sg[h0], g1 = sg[h1];
        float be0 = sbe[h0], be1 = sbe[h1];
#pragma unroll
        for (int r = 0; r < RPB; ++r) {
            int row = min(row0 + r, B - 1);
            size_t base = (size_t)row * OBS;
            float t0 = b0, t1 = b1;
#pragma unroll
            for (int k = 0; k < 4; ++k) {
                float xk = in[base + k];
                t0 = fmaf(xk, w0[k], t0);
                t1 = fmaf(xk, w1[k], t1);
            }
            t0 = fast_tanh(t0); t1 = fast_tanh(t1);
            float sa = wave_sum(t0 + act1f*t1);
            float sq = wave_sum(t0*t0 + act1f*(t1*t1));
            float mean = sa*0.01f;
            float var  = sq*0.01f - mean*mean;
            float rinv = __builtin_amdgcn_rsqf(var + 1e-5f);
            s_emb[r][h0] = (t0-mean)*rinv*g0 + be0;
            if (act1) s_emb[r][lane+64] = (t1-mean)*rinv*g1 + be1;
        }
    }

    // ---- qa = emb@Ac, ql = emb@Lc, tg = emb@fcW (fused k-loop) ----
    float qa0[RPB], qa1[RPB], ql0[RPB], ql1[RPB], tg0[RPB], tg1[RPB];
#pragma unroll
    for (int r = 0; r < RPB; ++r) { qa0[r]=qa1[r]=ql0[r]=ql1[r]=tg0[r]=tg1[r]=0.f; }
#pragma unroll 1
    for (int k4 = 0; k4 < 25; ++k4) {
        float4 sv[RPB];
#pragma unroll
        for (int r = 0; r < RPB; ++r) sv[r] = *(const float4*)&s_emb[r][k4*4];
#pragma unroll
        for (int j = 0; j < 4; ++j) {
            int k = k4*4 + j;
            float a0 = Ac[k*100+h0],  a1 = Ac[k*100+h1];
            float l0 = Lc[k*100+h0],  l1 = Lc[k*100+h1];
            float f0 = fcW[k*100+h0], f1 = fcW[k*100+h1];
#pragma unroll
            for (int r = 0; r < RPB; ++r) {
                float sk = f4c(sv[r], j);
                qa0[r] = fmaf(sk, a0, qa0[r]);
                qa1[r] = fmaf(sk, a1, qa1[r]);
                ql0[r] = fmaf(sk, l0, ql0[r]);
                ql1[r] = fmaf(sk, l1, ql1[r]);
                tg0[r] = fmaf(sk, f0, tg0[r]);
                tg1[r] = fmaf(sk, f1, tg1[r]);
            }
        }
    }

    // ---- gi = LN(tanh(tg + fcb)) -> s_x4[:, 0:100] ----
    {
        float b0 = fcb[h0], b1 = fcb[h1];
        float g0 = fcg[h0], g1 = fcg[h1];
        float be0 = fcbe[h0], be1 = fcbe[h1];
#pragma unroll
        for (int r = 0; r < RPB; ++r) {
            float t0 = fast_tanh(tg0[r] + b0);
            float t1 = fast_tanh(tg1[r] + b1);
            float sa = wave_sum(t0 + act1f*t1);
            float sq = wave_sum(t0*t0 + act1f*(t1*t1));
            float mean = sa*0.01f;
            float var  = sq*0.01f - mean*mean;
            float rinv = __builtin_amdgcn_rsqf(var + 1e-5f);
            s_x4[r][h0] = (t0-mean)*rinv*g0 + be0;
            if (act1) s_x4[r][lane+64] = (t1-mean)*rinv*g1 + be1;
        }
    }

    // ---- attention streams (ql reused for goal per ref bug) ----
    attn_stream<2,15>(oW, ob, og,  obe, in, row0, B, 52, qa0, qa1, s_x4, 100, h0, h1, act1f, act1, lane);
    attn_stream<3,16>(lW, lb, lg,  lbe, in, row0, B, 4,  ql0, ql1, s_x4, 200, h0, h1, act1f, act1, lane);
    attn_stream<2,16>(gW, gb, gg_, gbe, in, row0, B, 82, ql0, ql1, s_x4, 300, h0, h1, act1f, act1, lane);

    // ---- f1: [400] -> [100] ----
    float t10[RPB], t11[RPB];
#pragma unroll
    for (int r = 0; r < RPB; ++r) { t10[r]=0.f; t11[r]=0.f; }
#pragma unroll 1
    for (int k4 = 0; k4 < 100; ++k4) {
        float4 xv[RPB];
#pragma unroll
        for (int r = 0; r < RPB; ++r) xv[r] = *(const float4*)&s_x4[r][k4*4];
#pragma unroll
        for (int j = 0; j < 4; ++j) {
            int k = k4*4 + j;
            float w0 = f1W[k*100+h0], w1 = f1W[k*100+h1];
#pragma unroll
            for (int r = 0; r < RPB; ++r) {
                float xk = f4c(xv[r], j);
                t10[r] = fmaf(xk, w0, t10[r]);
                t11[r] = fmaf(xk, w1, t11[r]);
            }
        }
    }
    {
        float b0 = f1b[h0], b1 = f1b[h1];
        float g0 = f1g[h0], g1 = f1g[h1];
        float be0 = f1be[h0], be1 = f1be[h1];
#pragma unroll
        for (int r = 0; r < RPB; ++r) {
            float t0 = fast_tanh(t10[r] + b0);
            float t1 = fast_tanh(t11[r] + b1);
            float sa = wave_sum(t0 + act1f*t1);
            float sq = wave_sum(t0*t0 + act1f*(t1*t1));
            float mean = sa*0.01f;
            float var  = sq*0.01f - mean*mean;
            float rinv = __builtin_amdgcn_rsqf(var + 1e-5f);
            s_emb[r][h0] = (t0-mean)*rinv*g0 + be0;       // h1 reuses s_emb
            if (act1) s_emb[r][lane+64] = (t1-mean)*rinv*g1 + be1;
        }
    }

    // ---- f2: [100] -> [100] -> out ----
    float t20[RPB], t21[RPB];
#pragma unroll
    for (int r = 0; r < RPB; ++r) { t20[r]=0.f; t21[r]=0.f; }
#pragma unroll 1
    for (int k4 = 0; k4 < 25; ++k4) {
        float4 hv[RPB];
#pragma unroll
        for (int r = 0; r < RPB; ++r) hv[r] = *(const float4*)&s_emb[r][k4*4];
#pragma unroll
        for (int j = 0; j < 4; ++j) {
            int k = k4*4 + j;
            float w0 = f2W[k*100+h0], w1 = f2W[k*100+h1];
#pragma unroll
            for (int r = 0; r < RPB; ++r) {
                float xk = f4c(hv[r], j);
                t20[r] = fmaf(xk, w0, t20[r]);
                t21[r] = fmaf(xk, w1, t21[r]);
            }
        }
    }
    {
        float b0 = f2b[h0], b1 = f2b[h1];
        float g0 = f2g[h0], g1 = f2g[h1];
        float be0 = f2be[h0], be1 = f2be[h1];
#pragma unroll
        for (int r = 0; r < RPB; ++r) {
            int row = row0 + r;
            float t0 = fast_tanh(t20[r] + b0);
            float t1 = fast_tanh(t21[r] + b1);
            float sa = wave_sum(t0 + act1f*t1);
            float sq = wave_sum(t0*t0 + act1f*(t1*t1));
            float mean = sa*0.01f;
            float var  = sq*0.01f - mean*mean;
            float rinv = __builtin_amdgcn_rsqf(var + 1e-5f);
            if (row < B) {
                out[(size_t)row*100 + h0] = (t0-mean)*rinv*g0 + be0;
                if (act1) out[(size_t)row*100 + lane + 64] = (t1-mean)*rinv*g1 + be1;
            }
        }
    }
}

extern "C" void kernel_launch(void* const* d_in, const int* in_sizes, int n_in,
                              void* d_out, int out_size, void* d_ws, size_t ws_size,
                              hipStream_t stream) {
    const float* in  = (const float*)d_in[0];
    // d_in[1] is agent_num (N=16 hardcoded via template params / offsets)
    const float* sW  = (const float*)d_in[2];
    const float* sb  = (const float*)d_in[3];
    const float* sg  = (const float*)d_in[4];
    const float* sbe = (const float*)d_in[5];
    const float* oW  = (const float*)d_in[6];
    const float* ob  = (const float*)d_in[7];
    const float* og  = (const float*)d_in[8];
    const float* obe = (const float*)d_in[9];
    const float* lW  = (const float*)d_in[10];
    const float* lb  = (const float*)d_in[11];
    const float* lg  = (const float*)d_in[12];
    const float* lbe = (const float*)d_in[13];
    const float* gW  = (const float*)d_in[14];
    const float* gb  = (const float*)d_in[15];
    const float* gg  = (const float*)d_in[16];
    const float* gbe = (const float*)d_in[17];
    const float* Ac  = (const float*)d_in[18];
    const float* Lc  = (const float*)d_in[19];
    const float* fcW = (const float*)d_in[20];
    const float* fcb = (const float*)d_in[21];
    const float* fcg = (const float*)d_in[22];
    const float* fcbe= (const float*)d_in[23];
    const float* f1W = (const float*)d_in[24];
    const float* f1b = (const float*)d_in[25];
    const float* f1g = (const float*)d_in[26];
    const float* f1be= (const float*)d_in[27];
    const float* f2W = (const float*)d_in[28];
    const float* f2b = (const float*)d_in[29];
    const float* f2g = (const float*)d_in[30];
    const float* f2be= (const float*)d_in[31];
    float* out = (float*)d_out;

    int B = in_sizes[0] / OBS;
    int blocks = (B + RPB - 1) / RPB;
    obs_encoder_kernel<<<blocks, 64, 0, stream>>>(in,
        sW, sb, sg, sbe, oW, ob, og, obe, lW, lb, lg, lbe, gW, gb, gg, gbe,
        Ac, Lc, fcW, fcb, fcg, fcbe, f1W, f1b, f1g, f1be, f2W, f2b, f2g, f2be,
        out, B);
}

// Round 3
// 427.073 us; speedup vs baseline: 1.3403x; 1.3041x over previous
//
#include <hip/hip_runtime.h>
#include <math.h>

#define OBS 114
#define ROWS_PER_BLOCK 16   // 2 waves x 8 rows

__device__ __forceinline__ float fast_tanh(float x) {
    float e = __expf(2.0f * x);
    return 1.0f - 2.0f * __builtin_amdgcn_rcpf(e + 1.0f);
}

template<int CTRL>
__device__ __forceinline__ float dpp_add(float x) {
    int y = __builtin_amdgcn_update_dpp(0, __float_as_int(x), CTRL, 0xF, 0xF, true);
    return x + __int_as_float(y);
}
// sum across each 16-lane row (serves 4 rows per wave simultaneously)
__device__ __forceinline__ float row16_sum(float x) {
    x = dpp_add<0xB1>(x);    // quad_perm xor1
    x = dpp_add<0x4E>(x);    // quad_perm xor2
    x = dpp_add<0x124>(x);   // row_ror:4
    x = dpp_add<0x128>(x);   // row_ror:8
    return x;
}
__device__ __forceinline__ float f4c(const float4& v, int j) {
    return j==0?v.x: j==1?v.y: j==2?v.z: v.w;
}

// ---- repack [K x 100] row-major weights into [K][16 j][8 i] so each lane's
// 7 h-slots (h = j+16i) are 2 contiguous float4 loads ----
__global__ __launch_bounds__(256) void repack_kernel(
    const float* __restrict__ Ac, const float* __restrict__ Lc,
    const float* __restrict__ fcW, const float* __restrict__ f1W,
    const float* __restrict__ f2W, float* __restrict__ ws)
{
    int tid = blockIdx.x*256 + threadIdx.x;   // 800 krows * 128
    if (tid >= 800*128) return;
    int krow = tid >> 7;
    int idx  = tid & 127;
    int j = idx >> 3, i = idx & 7;
    int h = j + 16*i;
    const float* src; int k;
    if (krow < 100)      { src = Ac;  k = krow; }
    else if (krow < 200) { src = Lc;  k = krow-100; }
    else if (krow < 300) { src = fcW; k = krow-200; }
    else if (krow < 700) { src = f1W; k = krow-300; }
    else                 { src = f2W; k = krow-700; }
    float v = (i < 7 && h < 100) ? src[k*100 + h] : 0.f;
    ws[tid] = v;
}

// acc[i][b] = sum_k s_x4[R_b][k] * Wp[k][j][i]   (both row-batches share weights)
template<int NK4>
__device__ __forceinline__ void mm16(const float* __restrict__ Wp,
    const float (*s_x4)[400], int R0, int R1, int j, float acc[7][2])
{
#pragma unroll
    for (int i=0;i<7;++i) { acc[i][0]=0.f; acc[i][1]=0.f; }
#pragma unroll 1
    for (int k4 = 0; k4 < NK4; ++k4) {
        float4 xa = *(const float4*)&s_x4[R0][k4*4];
        float4 xb = *(const float4*)&s_x4[R1][k4*4];
#pragma unroll
        for (int jj=0;jj<4;++jj) {
            int k = k4*4+jj;
            const float* wp = Wp + k*128 + j*8;
            float4 wlo = *(const float4*)(wp);
            float4 whi = *(const float4*)(wp+4);
            float w[7] = {wlo.x,wlo.y,wlo.z,wlo.w,whi.x,whi.y,whi.z};
            float xka = f4c(xa,jj), xkb = f4c(xb,jj);
#pragma unroll
            for (int i=0;i<7;++i) {
                acc[i][0] = fmaf(xka, w[i], acc[i][0]);
                acc[i][1] = fmaf(xkb, w[i], acc[i][1]);
            }
        }
    }
}

// attention stream, 16-lane layout, no-max softmax, value-accum algebra:
// va_h = g_h*((sum_n w_n*rinv_n*t_nh) - (sum_n w_n*rinv_n*mean_n))/s + be_h
template<int K, int NA>
__device__ __forceinline__ void attn16(
    const float* __restrict__ W, const float* __restrict__ bb,
    const float* __restrict__ gp, const float* __restrict__ bep,
    const float* __restrict__ in, int xoff,
    float (*s_x4)[400], int seg,
    int rowAc, int rowBc, int RA, int RB,
    const int hc[7], const float msk[7])
{
    float w[K][7], bias[7], g[7], be[7];
#pragma unroll
    for (int i=0;i<7;++i) {
#pragma unroll
        for (int k=0;k<K;++k) w[k][i] = W[k*100 + hc[i]];
        bias[i] = bb[hc[i]]; g[i] = gp[hc[i]]; be[i] = bep[hc[i]];
    }
#pragma unroll 1
    for (int b=0; b<2; ++b) {
        int row = b ? rowBc : rowAc;
        int R   = b ? RB : RA;
        float qg[7];
#pragma unroll
        for (int i=0;i<7;++i) qg[i] = s_x4[R][seg + hc[i]] * msk[i];
        float C1 = row16_sum(qg[0]+qg[1]+qg[2]+qg[3]+qg[4]+qg[5]+qg[6]);
        const float* xrow = in + (size_t)row*OBS + xoff;
        float s = 0.f, bacc = 0.f, A[7];
#pragma unroll
        for (int i=0;i<7;++i) A[i]=0.f;
#pragma unroll 1
        for (int n=0;n<NA;++n) {
            float x[K];
#pragma unroll
            for (int k=0;k<K;++k) x[k] = xrow[n*K + k];
            float t[7], sa=0.f, sq=0.f, sd=0.f;
#pragma unroll
            for (int i=0;i<7;++i) {
                float a = bias[i];
#pragma unroll
                for (int k=0;k<K;++k) a = fmaf(x[k], w[k][i], a);
                float tt = fast_tanh(a) * msk[i];
                t[i] = tt;
                sa += tt;
                sq = fmaf(tt,tt,sq);
                sd = fmaf(qg[i],tt,sd);
            }
            sa = row16_sum(sa); sq = row16_sum(sq); sd = row16_sum(sd);
            float mean = sa*0.01f;
            float var  = fmaf(sq, 0.01f, -mean*mean);
            float rinv = __builtin_amdgcn_rsqf(var + 1e-5f);
            float logit = (sd - mean*C1)*rinv;      // q.be term is agent-constant -> dropped
            float wgt = __expf(fminf(logit, 80.f));
            s += wgt;
            float wr = wgt*rinv;
            bacc = fmaf(wr, mean, bacc);
#pragma unroll
            for (int i=0;i<7;++i) A[i] = fmaf(wr, t[i], A[i]);
        }
        float inv = __builtin_amdgcn_rcpf(s);
#pragma unroll
        for (int i=0;i<7;++i)
            if (msk[i] > 0.f) s_x4[R][seg + hc[i]] = fmaf(g[i], (A[i]-bacc)*inv, be[i]);
    }
}

__global__ __launch_bounds__(128)
void obs_encoder_kernel(const float* __restrict__ in,
    const float* __restrict__ sW, const float* __restrict__ sb, const float* __restrict__ sg, const float* __restrict__ sbe,
    const float* __restrict__ oW, const float* __restrict__ ob, const float* __restrict__ og, const float* __restrict__ obe,
    const float* __restrict__ lW, const float* __restrict__ lb, const float* __restrict__ lg, const float* __restrict__ lbe,
    const float* __restrict__ gW, const float* __restrict__ gb, const float* __restrict__ gg_, const float* __restrict__ gbe,
    const float* __restrict__ fcb, const float* __restrict__ fcg, const float* __restrict__ fcbe,
    const float* __restrict__ f1b, const float* __restrict__ f1g, const float* __restrict__ f1be,
    const float* __restrict__ f2b, const float* __restrict__ f2g, const float* __restrict__ f2be,
    const float* __restrict__ wsf,
    float* __restrict__ out, int B)
{
    const int lane = threadIdx.x & 63;
    const int wv   = threadIdx.x >> 6;
    const int j    = lane & 15;
    const int rw   = lane >> 4;
    const int rowBase = blockIdx.x*ROWS_PER_BLOCK + wv*8;
    const int rowA = rowBase + rw;        // batch 0
    const int rowB = rowBase + 4 + rw;    // batch 1
    const int RA = wv*8 + rw, RB = RA + 4;
    const int rowAc = min(rowA, B-1), rowBc = min(rowB, B-1);

    int hc[7]; float msk[7];
#pragma unroll
    for (int i=0;i<7;++i) {
        int h = j + 16*i;
        bool v = h < 100;
        hc[i] = v ? h : 99;
        msk[i] = v ? 1.f : 0.f;
    }

    // segments: [0:100) emb -> gi -> h1 (serial reuse), [100:200) qga->va,
    // [200:300) qgl->vl, [300:400) qgg->vg.  Waves touch disjoint R -> no barriers.
    __shared__ __align__(16) float s_x4[ROWS_PER_BLOCK][400];

    const float* Acp = wsf;
    const float* Lcp = wsf + 12800;
    const float* fcp = wsf + 25600;
    const float* f1p = wsf + 38400;
    const float* f2p = wsf + 89600;

    // ---- self encoder -> s_x4[:, 0:100] ----
    {
        float w[4][7], bias[7], g[7], be[7];
#pragma unroll
        for (int i=0;i<7;++i) {
#pragma unroll
            for (int k=0;k<4;++k) w[k][i] = sW[k*100 + hc[i]];
            bias[i] = sb[hc[i]]; g[i] = sg[hc[i]]; be[i] = sbe[hc[i]];
        }
#pragma unroll 1
        for (int b=0;b<2;++b) {
            int row = b ? rowBc : rowAc;
            int R   = b ? RB : RA;
            const float* xr = in + (size_t)row*OBS;
            float x0=xr[0], x1=xr[1], x2=xr[2], x3=xr[3];
            float t[7], sa=0.f, sq=0.f;
#pragma unroll
            for (int i=0;i<7;++i) {
                float a = bias[i];
                a = fmaf(x0, w[0][i], a); a = fmaf(x1, w[1][i], a);
                a = fmaf(x2, w[2][i], a); a = fmaf(x3, w[3][i], a);
                float tt = fast_tanh(a) * msk[i];
                t[i] = tt; sa += tt; sq = fmaf(tt,tt,sq);
            }
            sa = row16_sum(sa); sq = row16_sum(sq);
            float mean = sa*0.01f;
            float var  = fmaf(sq, 0.01f, -mean*mean);
            float rinv = __builtin_amdgcn_rsqf(var + 1e-5f);
#pragma unroll
            for (int i=0;i<7;++i)
                if (msk[i] > 0.f) s_x4[R][hc[i]] = fmaf((t[i]-mean)*rinv, g[i], be[i]);
        }
    }

    // ---- qa = emb@Ac -> qga = qa*og -> seg 100 ----
    {
        float acc[7][2];
        mm16<25>(Acp, s_x4, RA, RB, j, acc);
        float og7[7];
#pragma unroll
        for (int i=0;i<7;++i) og7[i] = og[hc[i]];
#pragma unroll
        for (int b=0;b<2;++b) {
            int R = b ? RB : RA;
#pragma unroll
            for (int i=0;i<7;++i)
                if (msk[i] > 0.f) s_x4[R][100 + hc[i]] = acc[i][b]*og7[i];
        }
    }
    // ---- ql = emb@Lc -> qgl = ql*lg -> seg 200, qgg = ql*gg -> seg 300 ----
    {
        float acc[7][2];
        mm16<25>(Lcp, s_x4, RA, RB, j, acc);
        float lg7[7], gg7[7];
#pragma unroll
        for (int i=0;i<7;++i) { lg7[i] = lg[hc[i]]; gg7[i] = gg_[hc[i]]; }
#pragma unroll
        for (int b=0;b<2;++b) {
            int R = b ? RB : RA;
#pragma unroll
            for (int i=0;i<7;++i)
                if (msk[i] > 0.f) {
                    s_x4[R][200 + hc[i]] = acc[i][b]*lg7[i];
                    s_x4[R][300 + hc[i]] = acc[i][b]*gg7[i];
                }
        }
    }
    // ---- gi = LN(tanh(emb@fcW + fcb)) -> seg 0 (overwrites emb; reads done) ----
    {
        float acc[7][2];
        mm16<25>(fcp, s_x4, RA, RB, j, acc);
        float bias[7], g[7], be[7];
#pragma unroll
        for (int i=0;i<7;++i) { bias[i]=fcb[hc[i]]; g[i]=fcg[hc[i]]; be[i]=fcbe[hc[i]]; }
#pragma unroll 1
        for (int b=0;b<2;++b) {
            int R = b ? RB : RA;
            float t[7], sa=0.f, sq=0.f;
#pragma unroll
            for (int i=0;i<7;++i) {
                float tt = fast_tanh(acc[i][b] + bias[i]) * msk[i];
                t[i] = tt; sa += tt; sq = fmaf(tt,tt,sq);
            }
            sa = row16_sum(sa); sq = row16_sum(sq);
            float mean = sa*0.01f;
            float var  = fmaf(sq, 0.01f, -mean*mean);
            float rinv = __builtin_amdgcn_rsqf(var + 1e-5f);
#pragma unroll
            for (int i=0;i<7;++i)
                if (msk[i] > 0.f) s_x4[R][hc[i]] = fmaf((t[i]-mean)*rinv, g[i], be[i]);
        }
    }

    // ---- attention streams (ql reused for goal per ref bug) ----
    attn16<2,15>(oW, ob, og,  obe, in, 52, s_x4, 100, rowAc, rowBc, RA, RB, hc, msk);
    attn16<3,16>(lW, lb, lg,  lbe, in, 4,  s_x4, 200, rowAc, rowBc, RA, RB, hc, msk);
    attn16<2,16>(gW, gb, gg_, gbe, in, 82, s_x4, 300, rowAc, rowBc, RA, RB, hc, msk);

    // ---- f1: [400] -> [100], LN -> seg 0 ----
    {
        float acc[7][2];
        mm16<100>(f1p, s_x4, RA, RB, j, acc);
        float bias[7], g[7], be[7];
#pragma unroll
        for (int i=0;i<7;++i) { bias[i]=f1b[hc[i]]; g[i]=f1g[hc[i]]; be[i]=f1be[hc[i]]; }
#pragma unroll 1
        for (int b=0;b<2;++b) {
            int R = b ? RB : RA;
            float t[7], sa=0.f, sq=0.f;
#pragma unroll
            for (int i=0;i<7;++i) {
                float tt = fast_tanh(acc[i][b] + bias[i]) * msk[i];
                t[i] = tt; sa += tt; sq = fmaf(tt,tt,sq);
            }
            sa = row16_sum(sa); sq = row16_sum(sq);
            float mean = sa*0.01f;
            float var  = fmaf(sq, 0.01f, -mean*mean);
            float rinv = __builtin_amdgcn_rsqf(var + 1e-5f);
#pragma unroll
            for (int i=0;i<7;++i)
                if (msk[i] > 0.f) s_x4[R][hc[i]] = fmaf((t[i]-mean)*rinv, g[i], be[i]);
        }
    }

    // ---- f2: [100] -> [100], LN -> out ----
    {
        float acc[7][2];
        mm16<25>(f2p, s_x4, RA, RB, j, acc);
        float bias[7], g[7], be[7];
#pragma unroll
        for (int i=0;i<7;++i) { bias[i]=f2b[hc[i]]; g[i]=f2g[hc[i]]; be[i]=f2be[hc[i]]; }
#pragma unroll 1
        for (int b=0;b<2;++b) {
            int row = b ? rowB : rowA;
            float t[7], sa=0.f, sq=0.f;
#pragma unroll
            for (int i=0;i<7;++i) {
                float tt = fast_tanh(acc[i][b] + bias[i]) * msk[i];
                t[i] = tt; sa += tt; sq = fmaf(tt,tt,sq);
            }
            sa = row16_sum(sa); sq = row16_sum(sq);
            float mean = sa*0.01f;
            float var  = fmaf(sq, 0.01f, -mean*mean);
            float rinv = __builtin_amdgcn_rsqf(var + 1e-5f);
            if (row < B) {
#pragma unroll
                for (int i=0;i<7;++i)
                    if (msk[i] > 0.f)
                        out[(size_t)row*100 + hc[i]] = fmaf((t[i]-mean)*rinv, g[i], be[i]);
            }
        }
    }
}

extern "C" void kernel_launch(void* const* d_in, const int* in_sizes, int n_in,
                              void* d_out, int out_size, void* d_ws, size_t ws_size,
                              hipStream_t stream) {
    const float* in  = (const float*)d_in[0];
    const float* sW  = (const float*)d_in[2];
    const float* sb  = (const float*)d_in[3];
    const float* sg  = (const float*)d_in[4];
    const float* sbe = (const float*)d_in[5];
    const float* oW  = (const float*)d_in[6];
    const float* ob  = (const float*)d_in[7];
    const float* og  = (const float*)d_in[8];
    const float* obe = (const float*)d_in[9];
    const float* lW  = (const float*)d_in[10];
    const float* lb  = (const float*)d_in[11];
    const float* lg  = (const float*)d_in[12];
    const float* lbe = (const float*)d_in[13];
    const float* gW  = (const float*)d_in[14];
    const float* gb  = (const float*)d_in[15];
    const float* gg  = (const float*)d_in[16];
    const float* gbe = (const float*)d_in[17];
    const float* Ac  = (const float*)d_in[18];
    const float* Lc  = (const float*)d_in[19];
    const float* fcW = (const float*)d_in[20];
    const float* fcb = (const float*)d_in[21];
    const float* fcg = (const float*)d_in[22];
    const float* fcbe= (const float*)d_in[23];
    const float* f1W = (const float*)d_in[24];
    const float* f1b = (const float*)d_in[25];
    const float* f1g = (const float*)d_in[26];
    const float* f1be= (const float*)d_in[27];
    const float* f2W = (const float*)d_in[28];
    const float* f2b = (const float*)d_in[29];
    const float* f2g = (const float*)d_in[30];
    const float* f2be= (const float*)d_in[31];
    float* out = (float*)d_out;
    float* wsf = (float*)d_ws;

    int B = in_sizes[0] / OBS;
    repack_kernel<<<(800*128 + 255)/256, 256, 0, stream>>>(Ac, Lc, fcW, f1W, f2W, wsf);
    int blocks = (B + ROWS_PER_BLOCK - 1) / ROWS_PER_BLOCK;
    obs_encoder_kernel<<<blocks, 128, 0, stream>>>(in,
        sW, sb, sg, sbe, oW, ob, og, obe, lW, lb, lg, lbe, gW, gb, gg, gbe,
        fcb, fcg, fcbe, f1b, f1g, f1be, f2b, f2g, f2be,
        wsf, out, B);
}

// Round 4
// 415.965 us; speedup vs baseline: 1.3761x; 1.0267x over previous
//
#include <hip/hip_runtime.h>
#include <math.h>

#define OBS 114
#define ROWS_PER_BLOCK 16   // 2 waves x 8 rows

__device__ __forceinline__ float fast_tanh(float x) {
    float e = __expf(2.0f * x);
    return 1.0f - 2.0f * __builtin_amdgcn_rcpf(e + 1.0f);
}

template<int CTRL>
__device__ __forceinline__ float dpp_add(float x) {
    int y = __builtin_amdgcn_update_dpp(0, __float_as_int(x), CTRL, 0xF, 0xF, true);
    return x + __int_as_float(y);
}
// sum across each 16-lane row (serves 4 rows per wave simultaneously)
__device__ __forceinline__ float row16_sum(float x) {
    x = dpp_add<0xB1>(x);    // quad_perm xor1
    x = dpp_add<0x4E>(x);    // quad_perm xor2
    x = dpp_add<0x124>(x);   // row_ror:4
    x = dpp_add<0x128>(x);   // row_ror:8
    return x;
}
__device__ __forceinline__ float f4c(const float4& v, int j) {
    return j==0?v.x: j==1?v.y: j==2?v.z: v.w;
}

// ---- repack [K x 100] row-major weights into [K][16 j][8 i] so each lane's
// 7 h-slots (h = j+16i) are 2 contiguous float4 loads ----
__global__ __launch_bounds__(256) void repack_kernel(
    const float* __restrict__ Ac, const float* __restrict__ Lc,
    const float* __restrict__ fcW, const float* __restrict__ f1W,
    const float* __restrict__ f2W, float* __restrict__ ws)
{
    int tid = blockIdx.x*256 + threadIdx.x;   // 800 krows * 128
    if (tid >= 800*128) return;
    int krow = tid >> 7;
    int idx  = tid & 127;
    int j = idx >> 3, i = idx & 7;
    int h = j + 16*i;
    const float* src; int k;
    if (krow < 100)      { src = Ac;  k = krow; }
    else if (krow < 200) { src = Lc;  k = krow-100; }
    else if (krow < 300) { src = fcW; k = krow-200; }
    else if (krow < 700) { src = f1W; k = krow-300; }
    else                 { src = f2W; k = krow-700; }
    float v = (i < 7 && h < 100) ? src[k*100 + h] : 0.f;
    ws[tid] = v;
}

// acc[i][b] = sum_k s_x4[R_b][k] * Wp[k][j][i]   (both row-batches share weights)
template<int NK4>
__device__ __forceinline__ void mm16(const float* __restrict__ Wp,
    const float (*s_x4)[400], int R0, int R1, int j, float acc[7][2])
{
#pragma unroll
    for (int i=0;i<7;++i) { acc[i][0]=0.f; acc[i][1]=0.f; }
#pragma unroll 1
    for (int k4 = 0; k4 < NK4; ++k4) {
        float4 xa = *(const float4*)&s_x4[R0][k4*4];
        float4 xb = *(const float4*)&s_x4[R1][k4*4];
#pragma unroll
        for (int jj=0;jj<4;++jj) {
            int k = k4*4+jj;
            const float* wp = Wp + k*128 + j*8;
            float4 wlo = *(const float4*)(wp);
            float4 whi = *(const float4*)(wp+4);
            float w[7] = {wlo.x,wlo.y,wlo.z,wlo.w,whi.x,whi.y,whi.z};
            float xka = f4c(xa,jj), xkb = f4c(xb,jj);
#pragma unroll
            for (int i=0;i<7;++i) {
                acc[i][0] = fmaf(xka, w[i], acc[i][0]);
                acc[i][1] = fmaf(xkb, w[i], acc[i][1]);
            }
        }
    }
}

// attention stream, 16-lane layout, batch-interleaved (2 independent chains),
// software-pipelined agent-input loads, q passed via registers.
// va_h = g_h*((sum_n w_n*rinv_n*t_nh) - (sum_n w_n*rinv_n*mean_n))/s + be_h
template<int K, int NA>
__device__ __forceinline__ void attn16(
    const float* __restrict__ W, const float* __restrict__ bb,
    const float* __restrict__ gp, const float* __restrict__ bep,
    const float* __restrict__ in, int xoff,
    float (*s_x4)[400], int seg,
    int rowAc, int rowBc, int RA, int RB,
    const float qacc[7][2],
    const int hc[7], const float msk[7])
{
    float w[K][7], bias[7], g[7], be[7];
#pragma unroll
    for (int i=0;i<7;++i) {
#pragma unroll
        for (int k=0;k<K;++k) w[k][i] = W[k*100 + hc[i]];
        bias[i] = bb[hc[i]]; g[i] = gp[hc[i]]; be[i] = bep[hc[i]];
    }
    float qg[2][7], C1[2];
#pragma unroll
    for (int b=0;b<2;++b) {
        float c = 0.f;
#pragma unroll
        for (int i=0;i<7;++i) { qg[b][i] = qacc[i][b]*g[i]*msk[i]; c += qg[b][i]; }
        C1[b] = row16_sum(c);
    }
    const float* xr0 = in + (size_t)rowAc*OBS + xoff;
    const float* xr1 = in + (size_t)rowBc*OBS + xoff;
    float s[2] = {0.f,0.f}, bacc[2] = {0.f,0.f};
    float A[2][7];
#pragma unroll
    for (int b=0;b<2;++b)
#pragma unroll
        for (int i=0;i<7;++i) A[b][i]=0.f;

    float xc[2][K];
#pragma unroll
    for (int k=0;k<K;++k) { xc[0][k] = xr0[k]; xc[1][k] = xr1[k]; }

#pragma unroll 1
    for (int n=0;n<NA;++n) {
        // prefetch next agent's inputs (depth-2 pipeline)
        int np = (n+1 < NA) ? (n+1) : n;
        float xn[2][K];
#pragma unroll
        for (int k=0;k<K;++k) { xn[0][k] = xr0[np*K+k]; xn[1][k] = xr1[np*K+k]; }

        float t[2][7], sa[2], sq[2], sd[2];
#pragma unroll
        for (int b=0;b<2;++b) { sa[b]=0.f; sq[b]=0.f; sd[b]=0.f; }
#pragma unroll
        for (int i=0;i<7;++i) {
#pragma unroll
            for (int b=0;b<2;++b) {
                float a = bias[i];
#pragma unroll
                for (int k=0;k<K;++k) a = fmaf(xc[b][k], w[k][i], a);
                float tt = fast_tanh(a) * msk[i];
                t[b][i] = tt;
                sa[b] += tt;
                sq[b] = fmaf(tt,tt,sq[b]);
                sd[b] = fmaf(qg[b][i],tt,sd[b]);
            }
        }
#pragma unroll
        for (int b=0;b<2;++b) { sa[b]=row16_sum(sa[b]); sq[b]=row16_sum(sq[b]); sd[b]=row16_sum(sd[b]); }
#pragma unroll
        for (int b=0;b<2;++b) {
            float mean = sa[b]*0.01f;
            float var  = fmaf(sq[b],0.01f,-mean*mean);
            float rinv = __builtin_amdgcn_rsqf(var + 1e-5f);
            float logit = (sd[b]-mean*C1[b])*rinv;   // q.be term agent-constant -> dropped
            float wgt = __expf(fminf(logit,80.f));
            s[b] += wgt;
            float wr = wgt*rinv;
            bacc[b] = fmaf(wr,mean,bacc[b]);
#pragma unroll
            for (int i=0;i<7;++i) A[b][i] = fmaf(wr,t[b][i],A[b][i]);
        }
#pragma unroll
        for (int k=0;k<K;++k) { xc[0][k]=xn[0][k]; xc[1][k]=xn[1][k]; }
    }
#pragma unroll
    for (int b=0;b<2;++b) {
        int R = b ? RB : RA;
        float inv = __builtin_amdgcn_rcpf(s[b]);
#pragma unroll
        for (int i=0;i<7;++i)
            if (msk[i]>0.f) s_x4[R][seg+hc[i]] = fmaf(g[i], (A[b][i]-bacc[b])*inv, be[i]);
    }
}

// LN(tanh(acc+bias)) for both batches, batch-interleaved
__device__ __forceinline__ void ln_pair(const float acc[7][2],
    const float* __restrict__ bp, const float* __restrict__ gp, const float* __restrict__ bep,
    const int hc[7], const float msk[7], float outv[2][7])
{
    float bias[7], g[7], be[7];
#pragma unroll
    for (int i=0;i<7;++i) { bias[i]=bp[hc[i]]; g[i]=gp[hc[i]]; be[i]=bep[hc[i]]; }
    float t[2][7], sa[2], sq[2];
#pragma unroll
    for (int b=0;b<2;++b) { sa[b]=0.f; sq[b]=0.f; }
#pragma unroll
    for (int i=0;i<7;++i) {
#pragma unroll
        for (int b=0;b<2;++b) {
            float tt = fast_tanh(acc[i][b] + bias[i]) * msk[i];
            t[b][i] = tt; sa[b] += tt; sq[b] = fmaf(tt,tt,sq[b]);
        }
    }
#pragma unroll
    for (int b=0;b<2;++b) { sa[b]=row16_sum(sa[b]); sq[b]=row16_sum(sq[b]); }
#pragma unroll
    for (int b=0;b<2;++b) {
        float mean = sa[b]*0.01f;
        float var  = fmaf(sq[b],0.01f,-mean*mean);
        float rinv = __builtin_amdgcn_rsqf(var + 1e-5f);
#pragma unroll
        for (int i=0;i<7;++i) outv[b][i] = fmaf((t[b][i]-mean)*rinv, g[i], be[i]);
    }
}

__global__ __launch_bounds__(128, 3)
void obs_encoder_kernel(const float* __restrict__ in,
    const float* __restrict__ sW, const float* __restrict__ sb, const float* __restrict__ sg, const float* __restrict__ sbe,
    const float* __restrict__ oW, const float* __restrict__ ob, const float* __restrict__ og, const float* __restrict__ obe,
    const float* __restrict__ lW, const float* __restrict__ lb, const float* __restrict__ lg, const float* __restrict__ lbe,
    const float* __restrict__ gW, const float* __restrict__ gb, const float* __restrict__ gg_, const float* __restrict__ gbe,
    const float* __restrict__ fcb, const float* __restrict__ fcg, const float* __restrict__ fcbe,
    const float* __restrict__ f1b, const float* __restrict__ f1g, const float* __restrict__ f1be,
    const float* __restrict__ f2b, const float* __restrict__ f2g, const float* __restrict__ f2be,
    const float* __restrict__ wsf,
    float* __restrict__ out, int B)
{
    const int lane = threadIdx.x & 63;
    const int wv   = threadIdx.x >> 6;
    const int j    = lane & 15;
    const int rw   = lane >> 4;
    const int rowBase = blockIdx.x*ROWS_PER_BLOCK + wv*8;
    const int rowA = rowBase + rw;        // batch 0
    const int rowB = rowBase + 4 + rw;    // batch 1
    const int RA = wv*8 + rw, RB = RA + 4;
    const int rowAc = min(rowA, B-1), rowBc = min(rowB, B-1);

    int hc[7]; float msk[7];
#pragma unroll
    for (int i=0;i<7;++i) {
        int h = j + 16*i;
        bool v = h < 100;
        hc[i] = v ? h : 99;
        msk[i] = v ? 1.f : 0.f;
    }

    // segments: [0:100) emb -> gi -> h1 (serial reuse), [100:200) va,
    // [200:300) vl, [300:400) vg.  Waves touch disjoint R -> no barriers.
    __shared__ __align__(16) float s_x4[ROWS_PER_BLOCK][400];

    const float* Acp = wsf;
    const float* Lcp = wsf + 12800;
    const float* fcp = wsf + 25600;
    const float* f1p = wsf + 38400;
    const float* f2p = wsf + 89600;

    // ---- self encoder -> s_x4[:, 0:100] ----
    {
        float w[4][7], bias[7], g[7], be[7];
#pragma unroll
        for (int i=0;i<7;++i) {
#pragma unroll
            for (int k=0;k<4;++k) w[k][i] = sW[k*100 + hc[i]];
            bias[i] = sb[hc[i]]; g[i] = sg[hc[i]]; be[i] = sbe[hc[i]];
        }
        const float* xr0 = in + (size_t)rowAc*OBS;
        const float* xr1 = in + (size_t)rowBc*OBS;
        float x[2][4];
#pragma unroll
        for (int k=0;k<4;++k) { x[0][k]=xr0[k]; x[1][k]=xr1[k]; }
        float t[2][7], sa[2], sq[2];
#pragma unroll
        for (int b=0;b<2;++b) { sa[b]=0.f; sq[b]=0.f; }
#pragma unroll
        for (int i=0;i<7;++i) {
#pragma unroll
            for (int b=0;b<2;++b) {
                float a = bias[i];
#pragma unroll
                for (int k=0;k<4;++k) a = fmaf(x[b][k], w[k][i], a);
                float tt = fast_tanh(a) * msk[i];
                t[b][i] = tt; sa[b] += tt; sq[b] = fmaf(tt,tt,sq[b]);
            }
        }
#pragma unroll
        for (int b=0;b<2;++b) { sa[b]=row16_sum(sa[b]); sq[b]=row16_sum(sq[b]); }
#pragma unroll
        for (int b=0;b<2;++b) {
            int R = b ? RB : RA;
            float mean = sa[b]*0.01f;
            float var  = fmaf(sq[b],0.01f,-mean*mean);
            float rinv = __builtin_amdgcn_rsqf(var + 1e-5f);
#pragma unroll
            for (int i=0;i<7;++i)
                if (msk[i] > 0.f) s_x4[R][hc[i]] = fmaf((t[b][i]-mean)*rinv, g[i], be[i]);
        }
    }

    // ---- qa = emb@Ac, ql = emb@Lc (kept in registers) ----
    float accA[7][2], accL[7][2];
    mm16<25>(Acp, s_x4, RA, RB, j, accA);
    mm16<25>(Lcp, s_x4, RA, RB, j, accL);

    // ---- gi = LN(tanh(emb@fcW + fcb)) -> seg 0 (overwrites emb) ----
    {
        float accF[7][2];
        mm16<25>(fcp, s_x4, RA, RB, j, accF);
        float outv[2][7];
        ln_pair(accF, fcb, fcg, fcbe, hc, msk, outv);
#pragma unroll
        for (int b=0;b<2;++b) {
            int R = b ? RB : RA;
#pragma unroll
            for (int i=0;i<7;++i)
                if (msk[i] > 0.f) s_x4[R][hc[i]] = outv[b][i];
        }
    }

    // ---- attention streams (ql reused for goal per ref bug) ----
    attn16<2,15>(oW, ob, og,  obe, in, 52, s_x4, 100, rowAc, rowBc, RA, RB, accA, hc, msk);
    attn16<3,16>(lW, lb, lg,  lbe, in, 4,  s_x4, 200, rowAc, rowBc, RA, RB, accL, hc, msk);
    attn16<2,16>(gW, gb, gg_, gbe, in, 82, s_x4, 300, rowAc, rowBc, RA, RB, accL, hc, msk);

    // ---- f1: [400] -> [100], LN -> seg 0 ----
    {
        float acc[7][2];
        mm16<100>(f1p, s_x4, RA, RB, j, acc);
        float outv[2][7];
        ln_pair(acc, f1b, f1g, f1be, hc, msk, outv);
#pragma unroll
        for (int b=0;b<2;++b) {
            int R = b ? RB : RA;
#pragma unroll
            for (int i=0;i<7;++i)
                if (msk[i] > 0.f) s_x4[R][hc[i]] = outv[b][i];
        }
    }

    // ---- f2: [100] -> [100], LN -> out ----
    {
        float acc[7][2];
        mm16<25>(f2p, s_x4, RA, RB, j, acc);
        float outv[2][7];
        ln_pair(acc, f2b, f2g, f2be, hc, msk, outv);
#pragma unroll
        for (int b=0;b<2;++b) {
            int row = b ? rowB : rowA;
            if (row < B) {
#pragma unroll
                for (int i=0;i<7;++i)
                    if (msk[i] > 0.f)
                        out[(size_t)row*100 + hc[i]] = outv[b][i];
            }
        }
    }
}

extern "C" void kernel_launch(void* const* d_in, const int* in_sizes, int n_in,
                              void* d_out, int out_size, void* d_ws, size_t ws_size,
                              hipStream_t stream) {
    const float* in  = (const float*)d_in[0];
    const float* sW  = (const float*)d_in[2];
    const float* sb  = (const float*)d_in[3];
    const float* sg  = (const float*)d_in[4];
    const float* sbe = (const float*)d_in[5];
    const float* oW  = (const float*)d_in[6];
    const float* ob  = (const float*)d_in[7];
    const float* og  = (const float*)d_in[8];
    const float* obe = (const float*)d_in[9];
    const float* lW  = (const float*)d_in[10];
    const float* lb  = (const float*)d_in[11];
    const float* lg  = (const float*)d_in[12];
    const float* lbe = (const float*)d_in[13];
    const float* gW  = (const float*)d_in[14];
    const float* gb  = (const float*)d_in[15];
    const float* gg  = (const float*)d_in[16];
    const float* gbe = (const float*)d_in[17];
    const float* Ac  = (const float*)d_in[18];
    const float* Lc  = (const float*)d_in[19];
    const float* fcW = (const float*)d_in[20];
    const float* fcb = (const float*)d_in[21];
    const float* fcg = (const float*)d_in[22];
    const float* fcbe= (const float*)d_in[23];
    const float* f1W = (const float*)d_in[24];
    const float* f1b = (const float*)d_in[25];
    const float* f1g = (const float*)d_in[26];
    const float* f1be= (const float*)d_in[27];
    const float* f2W = (const float*)d_in[28];
    const float* f2b = (const float*)d_in[29];
    const float* f2g = (const float*)d_in[30];
    const float* f2be= (const float*)d_in[31];
    float* out = (float*)d_out;
    float* wsf = (float*)d_ws;

    int B = in_sizes[0] / OBS;
    repack_kernel<<<(800*128 + 255)/256, 256, 0, stream>>>(Ac, Lc, fcW, f1W, f2W, wsf);
    int blocks = (B + ROWS_PER_BLOCK - 1) / ROWS_PER_BLOCK;
    obs_encoder_kernel<<<blocks, 128, 0, stream>>>(in,
        sW, sb, sg, sbe, oW, ob, og, obe, lW, lb, lg, lbe, gW, gb, gg, gbe,
        fcb, fcg, fcbe, f1b, f1g, f1be, f2b, f2g, f2be,
        wsf, out, B);
}